// Round 14
// baseline (27.793 us; speedup 1.0000x reference)
//
#include <hip/hip_runtime.h>

#define CC  256
#define HW  4096
#define HH  64
#define WW  64
#define RED 64
#define K2  49
#define NG  16
#define GCH 16

typedef __attribute__((ext_vector_type(8))) short bf16x8;
typedef __attribute__((ext_vector_type(4))) float f32x4;

__device__ inline unsigned short f2bf(float f) {
    union { float f; unsigned u; } v; v.f = f;
    unsigned r = v.u + 0x7FFF + ((v.u >> 16) & 1);   // round-to-nearest-even
    return (unsigned short)(r >> 16);
}

// lane i <- lane i-1 within each 16-lane row; invalid -> 0 (image left pad)
__device__ inline float dpp_shr1(float x) {
    union { float f; int i; } v; v.f = x;
    v.i = __builtin_amdgcn_mov_dpp(v.i, 0x111, 0xf, 0xf, true);
    return v.f;
}
// lane i <- lane i+1 within each 16-lane row; invalid -> 0 (image right pad)
__device__ inline float dpp_shl1(float x) {
    union { float f; int i; } v; v.f = x;
    v.i = __builtin_amdgcn_mov_dpp(v.i, 0x101, 0xf, 0xf, true);
    return v.f;
}

// ws layout (shorts):
//   tt    [b][y][x][r]  524288 elts at 0
//   w2bf  [832][64]      53248 elts at 524288
//   w1bf  [64][256]      16384 elts at 577536
#define TT_ELTS    524288
#define W2BF_ROWS  832
#define W2BF_OFF   524288
#define W1BF_OFF   577536
#define WS_NEED    ((524288 + 53248 + 16384) * 2)

// ================= Kernel 0: one-time weight conversion =================
// ids 0..2047: w1 8-chunks; 2048..8703: w2 8-chunks (zero-padded rows 784..831).
__global__ __launch_bounds__(256) void k0_prep(
    const float* __restrict__ w1,
    const float* __restrict__ w2,
    unsigned short* __restrict__ wsu)
{
    const int id = blockIdx.x * 256 + threadIdx.x;
    if (id < 2048) {                      // w1 -> bf16
        const float4 a = *reinterpret_cast<const float4*>(w1 + id * 8);
        const float4 b = *reinterpret_cast<const float4*>(w1 + id * 8 + 4);
        unsigned short r8[8] = {f2bf(a.x), f2bf(a.y), f2bf(a.z), f2bf(a.w),
                                f2bf(b.x), f2bf(b.y), f2bf(b.z), f2bf(b.w)};
        *reinterpret_cast<uint4*>(wsu + W1BF_OFF + id * 8) = *reinterpret_cast<const uint4*>(r8);
    } else if (id < 8704) {               // w2 -> bf16 (+ zero pad)
        const int c2 = id - 2048;
        unsigned short r8[8];
        if (c2 * 8 < K2 * NG * RED) {
            const float4 a = *reinterpret_cast<const float4*>(w2 + c2 * 8);
            const float4 b = *reinterpret_cast<const float4*>(w2 + c2 * 8 + 4);
            r8[0] = f2bf(a.x); r8[1] = f2bf(a.y); r8[2] = f2bf(a.z); r8[3] = f2bf(a.w);
            r8[4] = f2bf(b.x); r8[5] = f2bf(b.y); r8[6] = f2bf(b.z); r8[7] = f2bf(b.w);
        } else {
            #pragma unroll
            for (int i = 0; i < 8; ++i) r8[i] = 0;
        }
        *reinterpret_cast<uint4*>(wsu + W2BF_OFF + c2 * 8) = *reinterpret_cast<const uint4*>(r8);
    }
}

// ================= Kernel 1 (R9 verbatim): phase A via MFMA (w1 pre-converted) ========
// 256 blocks x 128 thr (2 waves); unit = bid*2 + wave (512 units).
// unit = (bb, y, nt): ONE wave: t[:, y, nt*16..+15] = relu(BN(w1 @ guide)).
__global__ __launch_bounds__(128) void k1_kernel(
    const float* __restrict__ guide,
    const unsigned short* __restrict__ wsu,
    const float* __restrict__ gamma,
    const float* __restrict__ beta,
    const float* __restrict__ mean,
    const float* __restrict__ var,
    unsigned short* __restrict__ tt)
{
    const int lane = threadIdx.x & 63;
    const int unit = blockIdx.x * 2 + __builtin_amdgcn_readfirstlane(threadIdx.x >> 6);

    const int bb = unit >> 8;
    const int y  = (unit >> 2) & 63;
    const int nt = unit & 3;
    const int lm = lane & 15;             // n-col / m-row within tile
    const int lg = lane >> 4;             // k-group
    const int px = nt * 16 + lm;

    const float* gcol = guide + (size_t)bb * CC * HW + (size_t)y * WW + px;
    const unsigned short* w1bf = wsu + W1BF_OFF;

    f32x4 acc[4] = {f32x4{0,0,0,0}, f32x4{0,0,0,0}, f32x4{0,0,0,0}, f32x4{0,0,0,0}};

    #pragma unroll
    for (int ks = 0; ks < 8; ++ks) {
        const int cbase = ks * 32 + lg * 8;
        union { unsigned short u[8]; bf16x8 v; } B;
        #pragma unroll
        for (int j = 0; j < 8; ++j)
            B.u[j] = f2bf(gcol[(size_t)(cbase + j) * HW]);
        #pragma unroll
        for (int mt = 0; mt < 4; ++mt) {
            const bf16x8 afr = *reinterpret_cast<const bf16x8*>(
                w1bf + (size_t)(mt * 16 + lm) * CC + cbase);
            acc[mt] = __builtin_amdgcn_mfma_f32_16x16x32_bf16(afr, B.v, acc[mt], 0, 0, 0);
        }
    }

    // epilogue: lane holds t[o = mt*16 + lg*4 + rr][px]; BN+ReLU -> bf16 -> Tt[px][o]
    const size_t ttrow = ((size_t)bb * HW + (size_t)y * WW + px) * RED;
    #pragma unroll
    for (int mt = 0; mt < 4; ++mt) {
        union { unsigned short u[4]; uint2 v; } R;
        #pragma unroll
        for (int rr = 0; rr < 4; ++rr) {
            const int o = mt * 16 + lg * 4 + rr;
            const float sc = gamma[o] * rsqrtf(var[o] + 1e-5f);
            const float sh = beta[o] - mean[o] * sc;
            float v = fmaf(acc[mt][rr], sc, sh);
            v = v > 0.f ? v : 0.f;
            R.u[rr] = f2bf(v);
        }
        *reinterpret_cast<uint2*>(tt + ttrow + mt * 16 + lg * 4) = R.v;
    }
}

// ================= Kernel 2 (R11 verbatim, launch_bounds 4): phase B + phase C ========
// grid: (bb, yp, g) = 2*32*16 = 1024 blocks, 256 thr (4 waves).
// Phase B: wave wv = (yh = wv>>1, nh = wv&1): y = y0+yh, n-tiles nh*2..+1; 16 MFMA.
// Phase C: thread = (cl = tid>>4, xq = tid&15): 1 channel x 4 px x 2 y;
//          L/R window elems come from neighbor lanes via DPP (1 float4 load/row).
__global__ __launch_bounds__(256, 4) void k2_inv_kernel(
    const float* __restrict__ feat,
    const unsigned short* __restrict__ tt,
    const unsigned short* __restrict__ w2bf,
    const float* __restrict__ b2,
    float* __restrict__ out)
{
    __shared__ float wg[2][K2][WW];       // 24.5 KB

    const int bid = blockIdx.x;
    const int bb  = bid >> 9;
    const int yp  = (bid >> 4) & 31;
    const int g   = bid & 15;
    const int y0  = yp * 2;
    const int tid  = threadIdx.x;
    const int lane = tid & 63;
    const int wv   = __builtin_amdgcn_readfirstlane(tid >> 6);
    const int lm = lane & 15;
    const int lg = lane >> 4;
    const int obase = g * K2;

    // ---- Phase B: wave (yh, nh) ----
    {
        const int yh = wv >> 1;
        const int nh = wv & 1;
        const int y  = y0 + yh;
        f32x4 acc[2][4];                  // [h][mt]
        #pragma unroll
        for (int h = 0; h < 2; ++h)
            #pragma unroll
            for (int mt = 0; mt < 4; ++mt) acc[h][mt] = f32x4{0, 0, 0, 0};

        #pragma unroll
        for (int h = 0; h < 2; ++h) {
            const int nt = nh * 2 + h;
            const size_t ttb = ((size_t)bb * HW + (size_t)y * WW + nt * 16 + lm) * RED + lg * 8;
            #pragma unroll
            for (int ks = 0; ks < 2; ++ks) {
                const bf16x8 bfr = *reinterpret_cast<const bf16x8*>(tt + ttb + ks * 32);
                #pragma unroll
                for (int mt = 0; mt < 4; ++mt) {
                    const bf16x8 afr = *reinterpret_cast<const bf16x8*>(
                        w2bf + (size_t)(obase + mt * 16 + lm) * RED + ks * 32 + lg * 8);
                    acc[h][mt] = __builtin_amdgcn_mfma_f32_16x16x32_bf16(afr, bfr, acc[h][mt], 0, 0, 0);
                }
            }
        }
        // C/D layout: col = lm -> x = nt*16+lm, row = lg*4+rr (+16 mt) -> o2
        #pragma unroll
        for (int h = 0; h < 2; ++h)
            #pragma unroll
            for (int mt = 0; mt < 4; ++mt)
                #pragma unroll
                for (int rr = 0; rr < 4; ++rr) {
                    const int o2 = mt * 16 + lg * 4 + rr;
                    if (o2 < K2)
                        wg[yh][o2][nh * 32 + h * 16 + lm] = acc[h][mt][rr] + b2[obase + o2];
                }
    }
    __syncthreads();

    // ---- Phase C: 1 channel x 4 px x 2 y per thread ----
    const int cl = tid >> 4;              // 0..15 (lane>>4 = 16-lane DPP row = channel)
    const int xq = tid & 15;              // 0..15
    const int x0 = xq * 4;
    const int c  = g * GCH + cl;
    const float* fb = feat + ((size_t)bb * CC + c) * HW;

    float s[2][4];
    #pragma unroll
    for (int ys = 0; ys < 2; ++ys)
        #pragma unroll
        for (int p = 0; p < 4; ++p) s[ys][p] = 0.f;

    #pragma unroll
    for (int dr = 0; dr < 8; ++dr) {      // absolute row r = y0 - 3 + dr
        const int r = y0 - 3 + dr;
        if (r < 0 || r >= HH) continue;   // block-uniform branch (full exec below)
        const float* fr = fb + (size_t)r * WW;

        const float4 M = *reinterpret_cast<const float4*>(fr + x0);
        // window buf[1..10]: neighbors via DPP (zero-fill = image pad at xq 0/15)
        const float b1 = dpp_shr1(M.y), b2e = dpp_shr1(M.z), b3 = dpp_shr1(M.w);
        const float b8 = dpp_shl1(M.x), b9  = dpp_shl1(M.y), b10 = dpp_shl1(M.z);
        const float buf[12] = {0.f, b1, b2e, b3, M.x, M.y, M.z, M.w, b8, b9, b10, 0.f};

        #pragma unroll
        for (int ys = 0; ys < 2; ++ys) {
            const int i = dr - ys;        // compile-time tap row
            if (i < 0 || i >= 7) continue;
            if (i == 3) {                 // residual (row y0+ys always in-bounds)
                s[ys][0] += buf[4]; s[ys][1] += buf[5];
                s[ys][2] += buf[6]; s[ys][3] += buf[7];
            }
            #pragma unroll
            for (int jx = 0; jx < 7; ++jx) {
                const float4 w4 = *reinterpret_cast<const float4*>(&wg[ys][i * 7 + jx][x0]);
                s[ys][0] = fmaf(w4.x, buf[jx + 1], s[ys][0]);
                s[ys][1] = fmaf(w4.y, buf[jx + 2], s[ys][1]);
                s[ys][2] = fmaf(w4.z, buf[jx + 3], s[ys][2]);
                s[ys][3] = fmaf(w4.w, buf[jx + 4], s[ys][3]);
            }
        }
    }

    #pragma unroll
    for (int ys = 0; ys < 2; ++ys) {
        float4 o4; o4.x = s[ys][0]; o4.y = s[ys][1]; o4.z = s[ys][2]; o4.w = s[ys][3];
        *reinterpret_cast<float4*>(out + ((size_t)bb * CC + c) * HW
                                   + (size_t)(y0 + ys) * WW + x0) = o4;
    }
}

// ================= Fallback: fused single kernel (used only if ws too small) =================
__global__ __launch_bounds__(512, 1) void crossinv_fused_kernel(
    const float* __restrict__ feat, const float* __restrict__ guide,
    const float* __restrict__ w1, const float* __restrict__ gamma,
    const float* __restrict__ beta, const float* __restrict__ mean,
    const float* __restrict__ var, const float* __restrict__ w2,
    const float* __restrict__ b2, float* __restrict__ out)
{
    __shared__ float stf[RED][WW];
    __shared__ float wgf[K2][WW];
    const int bid  = blockIdx.x;
    const int bb   = bid >> 7;
    const int y    = (bid >> 1) & 63;
    const int gsel = bid & 1;
    const int lane = threadIdx.x & 63;
    const int wv   = __builtin_amdgcn_readfirstlane(threadIdx.x >> 6);

    const float* gptr = guide + (size_t)bb * CC * HW + (size_t)y * WW + lane;
    float acc[8];
    #pragma unroll
    for (int j = 0; j < 8; ++j) acc[j] = 0.f;
    for (int c0 = 0; c0 < CC; c0 += 4) {
        const float gv0 = gptr[(c0 + 0) * HW];
        const float gv1 = gptr[(c0 + 1) * HW];
        const float gv2 = gptr[(c0 + 2) * HW];
        const float gv3 = gptr[(c0 + 3) * HW];
        #pragma unroll
        for (int j = 0; j < 8; ++j) {
            const int o = wv + 8 * j;
            const float4 wr = *reinterpret_cast<const float4*>(w1 + o * CC + c0);
            acc[j] = fmaf(wr.x, gv0, acc[j]);
            acc[j] = fmaf(wr.y, gv1, acc[j]);
            acc[j] = fmaf(wr.z, gv2, acc[j]);
            acc[j] = fmaf(wr.w, gv3, acc[j]);
        }
    }
    #pragma unroll
    for (int j = 0; j < 8; ++j) {
        const int o = wv + 8 * j;
        const float sc = gamma[o] * rsqrtf(var[o] + 1e-5f);
        const float sh = beta[o] - mean[o] * sc;
        const float v  = fmaf(acc[j], sc, sh);
        stf[o][lane] = v > 0.f ? v : 0.f;
    }
    __syncthreads();
    for (int gi = 0; gi < 8; ++gi) {
        const int gg    = gsel * 8 + gi;
        const int obase = gg * K2;
        float accw[7];
        #pragma unroll
        for (int j = 0; j < 7; ++j) {
            const int o2 = wv + 8 * j;
            accw[j] = (o2 < K2) ? b2[obase + o2] : 0.f;
        }
        for (int r0 = 0; r0 < RED; r0 += 4) {
            const float t0 = stf[r0 + 0][lane];
            const float t1 = stf[r0 + 1][lane];
            const float t2 = stf[r0 + 2][lane];
            const float t3 = stf[r0 + 3][lane];
            #pragma unroll
            for (int j = 0; j < 7; ++j) {
                const int o2 = wv + 8 * j;
                if (o2 < K2) {
                    const float4 wr = *reinterpret_cast<const float4*>(
                        w2 + (size_t)(obase + o2) * RED + r0);
                    accw[j] = fmaf(wr.x, t0, accw[j]);
                    accw[j] = fmaf(wr.y, t1, accw[j]);
                    accw[j] = fmaf(wr.z, t2, accw[j]);
                    accw[j] = fmaf(wr.w, t3, accw[j]);
                }
            }
        }
        #pragma unroll
        for (int j = 0; j < 7; ++j) {
            const int o2 = wv + 8 * j;
            if (o2 < K2) wgf[o2][lane] = accw[j];
        }
        __syncthreads();
        #pragma unroll
        for (int cc2 = 0; cc2 < 2; ++cc2) {
            const int cc = wv * 2 + cc2;
            const int cch = gg * GCH + cc;
            const float* fbp = feat + ((size_t)bb * CC + cch) * HW;
            float sum = fbp[y * WW + lane];
            #pragma unroll
            for (int i = 0; i < 7; ++i) {
                const int yy = y + i - 3;
                if (yy < 0 || yy >= HH) continue;
                const float* frow = fbp + yy * WW;
                #pragma unroll
                for (int jx = 0; jx < 7; ++jx) {
                    const int xx = lane + jx - 3;
                    const float fv = (xx >= 0 && xx < WW) ? frow[xx] : 0.f;
                    sum = fmaf(wgf[i * 7 + jx][lane], fv, sum);
                }
            }
            out[((size_t)bb * CC + cch) * HW + (size_t)y * WW + lane] = sum;
        }
        __syncthreads();
    }
}

extern "C" void kernel_launch(void* const* d_in, const int* in_sizes, int n_in,
                              void* d_out, int out_size, void* d_ws, size_t ws_size,
                              hipStream_t stream) {
    const float* feat  = (const float*)d_in[0];
    const float* guide = (const float*)d_in[1];
    const float* w1    = (const float*)d_in[2];
    const float* gamma = (const float*)d_in[3];
    const float* beta  = (const float*)d_in[4];
    const float* mean  = (const float*)d_in[5];
    const float* var   = (const float*)d_in[6];
    const float* w2    = (const float*)d_in[7];
    const float* b2    = (const float*)d_in[8];
    float* out = (float*)d_out;

    if (ws_size >= (size_t)WS_NEED) {
        unsigned short* wsu  = (unsigned short*)d_ws;
        unsigned short* tt   = wsu;
        unsigned short* w2bf = wsu + W2BF_OFF;
        hipLaunchKernelGGL(k0_prep, dim3(34), dim3(256), 0, stream, w1, w2, wsu);
        hipLaunchKernelGGL(k1_kernel, dim3(256), dim3(128), 0, stream,
                           guide, wsu, gamma, beta, mean, var, tt);
        hipLaunchKernelGGL(k2_inv_kernel, dim3(1024), dim3(256), 0, stream,
                           feat, tt, w2bf, b2, out);
    } else {
        hipLaunchKernelGGL(crossinv_fused_kernel, dim3(256), dim3(512), 0, stream,
                           feat, guide, w1, gamma, beta, mean, var, w2, b2, out);
    }
}

// Round 15
// 25.438 us; speedup vs baseline: 1.0925x; 1.0925x over previous
//
#include <hip/hip_runtime.h>

#define CC  256
#define HW  4096
#define HH  64
#define WW  64
#define RED 64
#define K2  49
#define NG  16
#define GCH 16

typedef __attribute__((ext_vector_type(8))) short bf16x8;
typedef __attribute__((ext_vector_type(4))) float f32x4;

__device__ inline unsigned short f2bf(float f) {
    union { float f; unsigned u; } v; v.f = f;
    unsigned r = v.u + 0x7FFF + ((v.u >> 16) & 1);   // round-to-nearest-even
    return (unsigned short)(r >> 16);
}

// lane i <- lane i-1 within each 16-lane row; invalid -> 0 (image left pad)
__device__ inline float dpp_shr1(float x) {
    union { float f; int i; } v; v.f = x;
    v.i = __builtin_amdgcn_mov_dpp(v.i, 0x111, 0xf, 0xf, true);
    return v.f;
}
// lane i <- lane i+1 within each 16-lane row; invalid -> 0 (image right pad)
__device__ inline float dpp_shl1(float x) {
    union { float f; int i; } v; v.f = x;
    v.i = __builtin_amdgcn_mov_dpp(v.i, 0x101, 0xf, 0xf, true);
    return v.f;
}

// ws layout: Tt bf16 [b][y][x][r]  (2*4096*64 = 524288 elts, 1 MB)
//            w2bf bf16 [832][64]   (53248 elts, rows 784.. zero pad) at +1 MB
#define TT_ELTS   524288
#define W2BF_ROWS 832

// ================= Kernel 1: phase A via MFMA, ks-split across 4 waves =================
// blocks 0..511: one (bb, y, nt) unit per BLOCK (256 thr). Wave w computes ks = 2w, 2w+1
//   (16 guide loads + 8 MFMA + partial acc), LDS-reduce, wave w owns mt=w epilogue.
// blocks 512..537: w2 -> bf16 conversion (thread-granular, 8-elt chunks).
__global__ __launch_bounds__(256) void k1_kernel(
    const float* __restrict__ guide,
    const float* __restrict__ w1,
    const float* __restrict__ gamma,
    const float* __restrict__ beta,
    const float* __restrict__ mean,
    const float* __restrict__ var,
    const float* __restrict__ w2,
    unsigned short* __restrict__ tt,
    unsigned short* __restrict__ w2bf)
{
    const int bid = blockIdx.x;
    const int tid = threadIdx.x;

    if (bid >= 512) {                     // ---- w2 -> bf16 (+ zero pad) ----
        const int idx = (bid - 512) * 256 + tid;      // 8-elt chunk id
        if (idx < (W2BF_ROWS * RED) / 8) {
            unsigned short r8[8];
            if (idx * 8 < K2 * NG * RED) {
                const float4 a = *reinterpret_cast<const float4*>(w2 + idx * 8);
                const float4 b = *reinterpret_cast<const float4*>(w2 + idx * 8 + 4);
                r8[0] = f2bf(a.x); r8[1] = f2bf(a.y); r8[2] = f2bf(a.z); r8[3] = f2bf(a.w);
                r8[4] = f2bf(b.x); r8[5] = f2bf(b.y); r8[6] = f2bf(b.z); r8[7] = f2bf(b.w);
            } else {
                #pragma unroll
                for (int i = 0; i < 8; ++i) r8[i] = 0;
            }
            *reinterpret_cast<uint4*>(w2bf + idx * 8) = *reinterpret_cast<const uint4*>(r8);
        }
        return;
    }

    __shared__ float4 red[4][4][64];      // [wave][mt][lane] partial acc, 16 KB

    const int lane = tid & 63;
    const int wv   = __builtin_amdgcn_readfirstlane(tid >> 6);
    const int bb = bid >> 8;
    const int y  = (bid >> 2) & 63;
    const int nt = bid & 3;
    const int lm = lane & 15;
    const int lg = lane >> 4;
    const int px = nt * 16 + lm;

    const float* gcol = guide + (size_t)bb * CC * HW + (size_t)y * WW + px;

    f32x4 acc[4] = {f32x4{0,0,0,0}, f32x4{0,0,0,0}, f32x4{0,0,0,0}, f32x4{0,0,0,0}};

    #pragma unroll
    for (int kk = 0; kk < 2; ++kk) {
        const int ks = wv * 2 + kk;
        const int cbase = ks * 32 + lg * 8;
        union { unsigned short u[8]; bf16x8 v; } B;
        #pragma unroll
        for (int j = 0; j < 8; ++j)
            B.u[j] = f2bf(gcol[(size_t)(cbase + j) * HW]);
        #pragma unroll
        for (int mt = 0; mt < 4; ++mt) {
            const float* ar = w1 + (size_t)(mt * 16 + lm) * CC + cbase;
            const float4 a0 = *reinterpret_cast<const float4*>(ar);
            const float4 a1 = *reinterpret_cast<const float4*>(ar + 4);
            union { unsigned short u[8]; bf16x8 v; } A;
            A.u[0] = f2bf(a0.x); A.u[1] = f2bf(a0.y);
            A.u[2] = f2bf(a0.z); A.u[3] = f2bf(a0.w);
            A.u[4] = f2bf(a1.x); A.u[5] = f2bf(a1.y);
            A.u[6] = f2bf(a1.z); A.u[7] = f2bf(a1.w);
            acc[mt] = __builtin_amdgcn_mfma_f32_16x16x32_bf16(A.v, B.v, acc[mt], 0, 0, 0);
        }
    }

    #pragma unroll
    for (int mt = 0; mt < 4; ++mt) {
        float4 p; p.x = acc[mt][0]; p.y = acc[mt][1]; p.z = acc[mt][2]; p.w = acc[mt][3];
        red[wv][mt][lane] = p;
    }
    __syncthreads();

    // wave wv reduces + stores mt = wv
    {
        const int mt = wv;
        const float4 p0 = red[0][mt][lane];
        const float4 p1 = red[1][mt][lane];
        const float4 p2 = red[2][mt][lane];
        const float4 p3 = red[3][mt][lane];
        float t0 = (p0.x + p1.x) + (p2.x + p3.x);
        float t1 = (p0.y + p1.y) + (p2.y + p3.y);
        float t2 = (p0.z + p1.z) + (p2.z + p3.z);
        float t3 = (p0.w + p1.w) + (p2.w + p3.w);

        const size_t ttrow = ((size_t)bb * HW + (size_t)y * WW + px) * RED;
        union { unsigned short u[4]; uint2 v; } R;
        const float tv[4] = {t0, t1, t2, t3};
        #pragma unroll
        for (int rr = 0; rr < 4; ++rr) {
            const int o = mt * 16 + lg * 4 + rr;
            const float sc = gamma[o] * rsqrtf(var[o] + 1e-5f);
            const float sh = beta[o] - mean[o] * sc;
            float v = fmaf(tv[rr], sc, sh);
            v = v > 0.f ? v : 0.f;
            R.u[rr] = f2bf(v);
        }
        *reinterpret_cast<uint2*>(tt + ttrow + mt * 16 + lg * 4) = R.v;
    }
}

// ================= Kernel 2 (R11 verbatim): phase B (MFMA) + phase C (DPP windows) ====
// grid: (bb, yp, g) = 2*32*16 = 1024 blocks, 256 thr (4 waves).
// Phase B: wave wv = (yh = wv>>1, nh = wv&1): y = y0+yh, n-tiles nh*2..+1; 16 MFMA.
// Phase C: thread = (cl = tid>>4, xq = tid&15): 1 channel x 4 px x 2 y;
//          L/R window elems come from neighbor lanes via DPP (1 float4 load/row).
__global__ __launch_bounds__(256, 3) void k2_inv_kernel(
    const float* __restrict__ feat,
    const unsigned short* __restrict__ tt,
    const unsigned short* __restrict__ w2bf,
    const float* __restrict__ b2,
    float* __restrict__ out)
{
    __shared__ float wg[2][K2][WW];       // 24.5 KB

    const int bid = blockIdx.x;
    const int bb  = bid >> 9;
    const int yp  = (bid >> 4) & 31;
    const int g   = bid & 15;
    const int y0  = yp * 2;
    const int tid  = threadIdx.x;
    const int lane = tid & 63;
    const int wv   = __builtin_amdgcn_readfirstlane(tid >> 6);
    const int lm = lane & 15;
    const int lg = lane >> 4;
    const int obase = g * K2;

    // ---- Phase B: wave (yh, nh) ----
    {
        const int yh = wv >> 1;
        const int nh = wv & 1;
        const int y  = y0 + yh;
        f32x4 acc[2][4];                  // [h][mt]
        #pragma unroll
        for (int h = 0; h < 2; ++h)
            #pragma unroll
            for (int mt = 0; mt < 4; ++mt) acc[h][mt] = f32x4{0, 0, 0, 0};

        #pragma unroll
        for (int h = 0; h < 2; ++h) {
            const int nt = nh * 2 + h;
            const size_t ttb = ((size_t)bb * HW + (size_t)y * WW + nt * 16 + lm) * RED + lg * 8;
            #pragma unroll
            for (int ks = 0; ks < 2; ++ks) {
                const bf16x8 bfr = *reinterpret_cast<const bf16x8*>(tt + ttb + ks * 32);
                #pragma unroll
                for (int mt = 0; mt < 4; ++mt) {
                    const bf16x8 afr = *reinterpret_cast<const bf16x8*>(
                        w2bf + (size_t)(obase + mt * 16 + lm) * RED + ks * 32 + lg * 8);
                    acc[h][mt] = __builtin_amdgcn_mfma_f32_16x16x32_bf16(afr, bfr, acc[h][mt], 0, 0, 0);
                }
            }
        }
        // C/D layout: col = lm -> x = nt*16+lm, row = lg*4+rr (+16 mt) -> o2
        #pragma unroll
        for (int h = 0; h < 2; ++h)
            #pragma unroll
            for (int mt = 0; mt < 4; ++mt)
                #pragma unroll
                for (int rr = 0; rr < 4; ++rr) {
                    const int o2 = mt * 16 + lg * 4 + rr;
                    if (o2 < K2)
                        wg[yh][o2][nh * 32 + h * 16 + lm] = acc[h][mt][rr] + b2[obase + o2];
                }
    }
    __syncthreads();

    // ---- Phase C: 1 channel x 4 px x 2 y per thread ----
    const int cl = tid >> 4;              // 0..15 (lane>>4 = 16-lane DPP row = channel)
    const int xq = tid & 15;              // 0..15
    const int x0 = xq * 4;
    const int c  = g * GCH + cl;
    const float* fb = feat + ((size_t)bb * CC + c) * HW;

    float s[2][4];
    #pragma unroll
    for (int ys = 0; ys < 2; ++ys)
        #pragma unroll
        for (int p = 0; p < 4; ++p) s[ys][p] = 0.f;

    #pragma unroll
    for (int dr = 0; dr < 8; ++dr) {      // absolute row r = y0 - 3 + dr
        const int r = y0 - 3 + dr;
        if (r < 0 || r >= HH) continue;   // block-uniform branch (full exec below)
        const float* fr = fb + (size_t)r * WW;

        const float4 M = *reinterpret_cast<const float4*>(fr + x0);
        // window buf[1..10]: neighbors via DPP (zero-fill = image pad at xq 0/15)
        const float b1 = dpp_shr1(M.y), b2e = dpp_shr1(M.z), b3 = dpp_shr1(M.w);
        const float b8 = dpp_shl1(M.x), b9  = dpp_shl1(M.y), b10 = dpp_shl1(M.z);
        const float buf[12] = {0.f, b1, b2e, b3, M.x, M.y, M.z, M.w, b8, b9, b10, 0.f};

        #pragma unroll
        for (int ys = 0; ys < 2; ++ys) {
            const int i = dr - ys;        // compile-time tap row
            if (i < 0 || i >= 7) continue;
            if (i == 3) {                 // residual (row y0+ys always in-bounds)
                s[ys][0] += buf[4]; s[ys][1] += buf[5];
                s[ys][2] += buf[6]; s[ys][3] += buf[7];
            }
            #pragma unroll
            for (int jx = 0; jx < 7; ++jx) {
                const float4 w4 = *reinterpret_cast<const float4*>(&wg[ys][i * 7 + jx][x0]);
                s[ys][0] = fmaf(w4.x, buf[jx + 1], s[ys][0]);
                s[ys][1] = fmaf(w4.y, buf[jx + 2], s[ys][1]);
                s[ys][2] = fmaf(w4.z, buf[jx + 3], s[ys][2]);
                s[ys][3] = fmaf(w4.w, buf[jx + 4], s[ys][3]);
            }
        }
    }

    #pragma unroll
    for (int ys = 0; ys < 2; ++ys) {
        float4 o4; o4.x = s[ys][0]; o4.y = s[ys][1]; o4.z = s[ys][2]; o4.w = s[ys][3];
        *reinterpret_cast<float4*>(out + ((size_t)bb * CC + c) * HW
                                   + (size_t)(y0 + ys) * WW + x0) = o4;
    }
}

// ================= Fallback: fused single kernel (used only if ws too small) =================
__global__ __launch_bounds__(512, 1) void crossinv_fused_kernel(
    const float* __restrict__ feat, const float* __restrict__ guide,
    const float* __restrict__ w1, const float* __restrict__ gamma,
    const float* __restrict__ beta, const float* __restrict__ mean,
    const float* __restrict__ var, const float* __restrict__ w2,
    const float* __restrict__ b2, float* __restrict__ out)
{
    __shared__ float stf[RED][WW];
    __shared__ float wgf[K2][WW];
    const int bid  = blockIdx.x;
    const int bb   = bid >> 7;
    const int y    = (bid >> 1) & 63;
    const int gsel = bid & 1;
    const int lane = threadIdx.x & 63;
    const int wv   = __builtin_amdgcn_readfirstlane(threadIdx.x >> 6);

    const float* gptr = guide + (size_t)bb * CC * HW + (size_t)y * WW + lane;
    float acc[8];
    #pragma unroll
    for (int j = 0; j < 8; ++j) acc[j] = 0.f;
    for (int c0 = 0; c0 < CC; c0 += 4) {
        const float gv0 = gptr[(c0 + 0) * HW];
        const float gv1 = gptr[(c0 + 1) * HW];
        const float gv2 = gptr[(c0 + 2) * HW];
        const float gv3 = gptr[(c0 + 3) * HW];
        #pragma unroll
        for (int j = 0; j < 8; ++j) {
            const int o = wv + 8 * j;
            const float4 wr = *reinterpret_cast<const float4*>(w1 + o * CC + c0);
            acc[j] = fmaf(wr.x, gv0, acc[j]);
            acc[j] = fmaf(wr.y, gv1, acc[j]);
            acc[j] = fmaf(wr.z, gv2, acc[j]);
            acc[j] = fmaf(wr.w, gv3, acc[j]);
        }
    }
    #pragma unroll
    for (int j = 0; j < 8; ++j) {
        const int o = wv + 8 * j;
        const float sc = gamma[o] * rsqrtf(var[o] + 1e-5f);
        const float sh = beta[o] - mean[o] * sc;
        const float v  = fmaf(acc[j], sc, sh);
        stf[o][lane] = v > 0.f ? v : 0.f;
    }
    __syncthreads();
    for (int gi = 0; gi < 8; ++gi) {
        const int gg    = gsel * 8 + gi;
        const int obase = gg * K2;
        float accw[7];
        #pragma unroll
        for (int j = 0; j < 7; ++j) {
            const int o2 = wv + 8 * j;
            accw[j] = (o2 < K2) ? b2[obase + o2] : 0.f;
        }
        for (int r0 = 0; r0 < RED; r0 += 4) {
            const float t0 = stf[r0 + 0][lane];
            const float t1 = stf[r0 + 1][lane];
            const float t2 = stf[r0 + 2][lane];
            const float t3 = stf[r0 + 3][lane];
            #pragma unroll
            for (int j = 0; j < 7; ++j) {
                const int o2 = wv + 8 * j;
                if (o2 < K2) {
                    const float4 wr = *reinterpret_cast<const float4*>(
                        w2 + (size_t)(obase + o2) * RED + r0);
                    accw[j] = fmaf(wr.x, t0, accw[j]);
                    accw[j] = fmaf(wr.y, t1, accw[j]);
                    accw[j] = fmaf(wr.z, t2, accw[j]);
                    accw[j] = fmaf(wr.w, t3, accw[j]);
                }
            }
        }
        #pragma unroll
        for (int j = 0; j < 7; ++j) {
            const int o2 = wv + 8 * j;
            if (o2 < K2) wgf[o2][lane] = accw[j];
        }
        __syncthreads();
        #pragma unroll
        for (int cc2 = 0; cc2 < 2; ++cc2) {
            const int cc = wv * 2 + cc2;
            const int cch = gg * GCH + cc;
            const float* fbp = feat + ((size_t)bb * CC + cch) * HW;
            float sum = fbp[y * WW + lane];
            #pragma unroll
            for (int i = 0; i < 7; ++i) {
                const int yy = y + i - 3;
                if (yy < 0 || yy >= HH) continue;
                const float* frow = fbp + yy * WW;
                #pragma unroll
                for (int jx = 0; jx < 7; ++jx) {
                    const int xx = lane + jx - 3;
                    const float fv = (xx >= 0 && xx < WW) ? frow[xx] : 0.f;
                    sum = fmaf(wgf[i * 7 + jx][lane], fv, sum);
                }
            }
            out[((size_t)bb * CC + cch) * HW + (size_t)y * WW + lane] = sum;
        }
        __syncthreads();
    }
}

extern "C" void kernel_launch(void* const* d_in, const int* in_sizes, int n_in,
                              void* d_out, int out_size, void* d_ws, size_t ws_size,
                              hipStream_t stream) {
    const float* feat  = (const float*)d_in[0];
    const float* guide = (const float*)d_in[1];
    const float* w1    = (const float*)d_in[2];
    const float* gamma = (const float*)d_in[3];
    const float* beta  = (const float*)d_in[4];
    const float* mean  = (const float*)d_in[5];
    const float* var   = (const float*)d_in[6];
    const float* w2    = (const float*)d_in[7];
    const float* b2    = (const float*)d_in[8];
    float* out = (float*)d_out;

    const size_t need = (size_t)TT_ELTS * 2 + (size_t)W2BF_ROWS * RED * 2;  // ~1.1 MB
    if (ws_size >= need) {
        unsigned short* tt   = (unsigned short*)d_ws;
        unsigned short* w2bf = tt + TT_ELTS;
        // 512 phase-A blocks (1 unit each, 4-wave ks-split) + 26 w2-cvt blocks
        hipLaunchKernelGGL(k1_kernel, dim3(538), dim3(256), 0, stream,
                           guide, w1, gamma, beta, mean, var, w2, tt, w2bf);
        hipLaunchKernelGGL(k2_inv_kernel, dim3(1024), dim3(256), 0, stream,
                           feat, tt, w2bf, b2, out);
    } else {
        hipLaunchKernelGGL(crossinv_fused_kernel, dim3(256), dim3(512), 0, stream,
                           feat, guide, w1, gamma, beta, mean, var, w2, b2, out);
    }
}

// Round 17
// 24.099 us; speedup vs baseline: 1.1532x; 1.0556x over previous
//
#include <hip/hip_runtime.h>

#define CC  256
#define HW  4096
#define HH  64
#define WW  64
#define RED 64
#define K2  49
#define NG  16
#define GCH 16

typedef __attribute__((ext_vector_type(8))) short bf16x8;
typedef __attribute__((ext_vector_type(4))) float f32x4;

__device__ inline unsigned short f2bf(float f) {
    union { float f; unsigned u; } v; v.f = f;
    unsigned r = v.u + 0x7FFF + ((v.u >> 16) & 1);   // round-to-nearest-even
    return (unsigned short)(r >> 16);
}

// lane i <- lane i-1 within each 16-lane row; invalid -> 0 (image left pad)
__device__ inline float dpp_shr1(float x) {
    union { float f; int i; } v; v.f = x;
    v.i = __builtin_amdgcn_mov_dpp(v.i, 0x111, 0xf, 0xf, true);
    return v.f;
}
// lane i <- lane i+1 within each 16-lane row; invalid -> 0 (image right pad)
__device__ inline float dpp_shl1(float x) {
    union { float f; int i; } v; v.f = x;
    v.i = __builtin_amdgcn_mov_dpp(v.i, 0x101, 0xf, 0xf, true);
    return v.f;
}

// ws layout: Tt bf16 [b][y][x][r]  (2*4096*64 = 524288 elts, 1 MB)
//            w2bf bf16 [832][64]   (53248 elts, rows 784.. zero pad) at +1 MB
#define TT_ELTS   524288
#define W2BF_ROWS 832

// ================= Kernel 1 (R8 verbatim): phase A via MFMA (+ w2->bf16 tail) =========
// 308 blocks x 128 thr (2 waves); unit = bid*2 + wave (616 units).
__global__ __launch_bounds__(128) void k1_kernel(
    const float* __restrict__ guide,
    const float* __restrict__ w1,
    const float* __restrict__ gamma,
    const float* __restrict__ beta,
    const float* __restrict__ mean,
    const float* __restrict__ var,
    const float* __restrict__ w2,
    unsigned short* __restrict__ tt,
    unsigned short* __restrict__ w2bf)
{
    const int lane = threadIdx.x & 63;
    const int unit = blockIdx.x * 2 + __builtin_amdgcn_readfirstlane(threadIdx.x >> 6);

    if (unit >= 512) {                    // ---- w2 -> bf16 (+ zero pad) ----
        const int idx = (unit - 512) * 64 + lane;     // 8-elt chunk id
        if (idx < (W2BF_ROWS * RED) / 8) {
            unsigned short r8[8];
            if (idx * 8 < K2 * NG * RED) {
                const float4 a = *reinterpret_cast<const float4*>(w2 + idx * 8);
                const float4 b = *reinterpret_cast<const float4*>(w2 + idx * 8 + 4);
                r8[0] = f2bf(a.x); r8[1] = f2bf(a.y); r8[2] = f2bf(a.z); r8[3] = f2bf(a.w);
                r8[4] = f2bf(b.x); r8[5] = f2bf(b.y); r8[6] = f2bf(b.z); r8[7] = f2bf(b.w);
            } else {
                #pragma unroll
                for (int i = 0; i < 8; ++i) r8[i] = 0;
            }
            *reinterpret_cast<uint4*>(w2bf + idx * 8) = *reinterpret_cast<const uint4*>(r8);
        }
        return;
    }

    const int bb = unit >> 8;
    const int y  = (unit >> 2) & 63;
    const int nt = unit & 3;
    const int lm = lane & 15;
    const int lg = lane >> 4;
    const int px = nt * 16 + lm;

    const float* gcol = guide + (size_t)bb * CC * HW + (size_t)y * WW + px;

    f32x4 acc[4] = {f32x4{0,0,0,0}, f32x4{0,0,0,0}, f32x4{0,0,0,0}, f32x4{0,0,0,0}};

    #pragma unroll
    for (int ks = 0; ks < 8; ++ks) {
        const int cbase = ks * 32 + lg * 8;
        union { unsigned short u[8]; bf16x8 v; } B;
        #pragma unroll
        for (int j = 0; j < 8; ++j)
            B.u[j] = f2bf(gcol[(size_t)(cbase + j) * HW]);
        #pragma unroll
        for (int mt = 0; mt < 4; ++mt) {
            const float* ar = w1 + (size_t)(mt * 16 + lm) * CC + cbase;
            const float4 a0 = *reinterpret_cast<const float4*>(ar);
            const float4 a1 = *reinterpret_cast<const float4*>(ar + 4);
            union { unsigned short u[8]; bf16x8 v; } A;
            A.u[0] = f2bf(a0.x); A.u[1] = f2bf(a0.y);
            A.u[2] = f2bf(a0.z); A.u[3] = f2bf(a0.w);
            A.u[4] = f2bf(a1.x); A.u[5] = f2bf(a1.y);
            A.u[6] = f2bf(a1.z); A.u[7] = f2bf(a1.w);
            acc[mt] = __builtin_amdgcn_mfma_f32_16x16x32_bf16(A.v, B.v, acc[mt], 0, 0, 0);
        }
    }

    const size_t ttrow = ((size_t)bb * HW + (size_t)y * WW + px) * RED;
    #pragma unroll
    for (int mt = 0; mt < 4; ++mt) {
        union { unsigned short u[4]; uint2 v; } R;
        #pragma unroll
        for (int rr = 0; rr < 4; ++rr) {
            const int o = mt * 16 + lg * 4 + rr;
            const float sc = gamma[o] * rsqrtf(var[o] + 1e-5f);
            const float sh = beta[o] - mean[o] * sc;
            float v = fmaf(acc[mt][rr], sc, sh);
            v = v > 0.f ? v : 0.f;
            R.u[rr] = f2bf(v);
        }
        *reinterpret_cast<uint2*>(tt + ttrow + mt * 16 + lg * 4) = R.v;
    }
}

// ================= Kernel 2: phase B (MFMA) + phase C, 2-row y-tile, DPP windows ======
// grid: (bb, yp, g) = 2*32*16 = 1024 blocks, 256 thr (4 waves).
// Phase B: wave wv = (yh = wv>>1, nh = wv&1): y = y0+yh, n-tiles nh*2..+1; 16 MFMA.
// Phase C: thread = (cl = tid>>4, xq = tid&15): 1 channel x 4 px x 2 y;
//          L/R window elems come from neighbor lanes via DPP (1 float4 load/row).
__global__ __launch_bounds__(256, 3) void k2_inv_kernel(
    const float* __restrict__ feat,
    const unsigned short* __restrict__ tt,
    const unsigned short* __restrict__ w2bf,
    const float* __restrict__ b2,
    float* __restrict__ out)
{
    __shared__ float wg[2][K2][WW];       // 24.5 KB

    const int bid = blockIdx.x;
    const int bb  = bid >> 9;
    const int yp  = (bid >> 4) & 31;
    const int g   = bid & 15;
    const int y0  = yp * 2;
    const int tid  = threadIdx.x;
    const int lane = tid & 63;
    const int wv   = __builtin_amdgcn_readfirstlane(tid >> 6);
    const int lm = lane & 15;
    const int lg = lane >> 4;
    const int obase = g * K2;

    // ---- Phase B: wave (yh, nh) ----
    {
        const int yh = wv >> 1;
        const int nh = wv & 1;
        const int y  = y0 + yh;
        f32x4 acc[2][4];                  // [h][mt]
        #pragma unroll
        for (int h = 0; h < 2; ++h)
            #pragma unroll
            for (int mt = 0; mt < 4; ++mt) acc[h][mt] = f32x4{0, 0, 0, 0};

        #pragma unroll
        for (int h = 0; h < 2; ++h) {
            const int nt = nh * 2 + h;
            const size_t ttb = ((size_t)bb * HW + (size_t)y * WW + nt * 16 + lm) * RED + lg * 8;
            #pragma unroll
            for (int ks = 0; ks < 2; ++ks) {
                const bf16x8 bfr = *reinterpret_cast<const bf16x8*>(tt + ttb + ks * 32);
                #pragma unroll
                for (int mt = 0; mt < 4; ++mt) {
                    const bf16x8 afr = *reinterpret_cast<const bf16x8*>(
                        w2bf + (size_t)(obase + mt * 16 + lm) * RED + ks * 32 + lg * 8);
                    acc[h][mt] = __builtin_amdgcn_mfma_f32_16x16x32_bf16(afr, bfr, acc[h][mt], 0, 0, 0);
                }
            }
        }
        // C/D layout: col = lm -> x = nt*16+lm, row = lg*4+rr (+16 mt) -> o2
        #pragma unroll
        for (int h = 0; h < 2; ++h)
            #pragma unroll
            for (int mt = 0; mt < 4; ++mt)
                #pragma unroll
                for (int rr = 0; rr < 4; ++rr) {
                    const int o2 = mt * 16 + lg * 4 + rr;
                    if (o2 < K2)
                        wg[yh][o2][nh * 32 + h * 16 + lm] = acc[h][mt][rr] + b2[obase + o2];
                }
    }
    __syncthreads();

    // ---- Phase C: 1 channel x 4 px x 2 y per thread ----
    const int cl = tid >> 4;              // 0..15 (lane>>4 = 16-lane DPP row = channel)
    const int xq = tid & 15;              // 0..15
    const int x0 = xq * 4;
    const int c  = g * GCH + cl;
    const float* fb = feat + ((size_t)bb * CC + c) * HW;

    float s[2][4];
    #pragma unroll
    for (int ys = 0; ys < 2; ++ys)
        #pragma unroll
        for (int p = 0; p < 4; ++p) s[ys][p] = 0.f;

    #pragma unroll
    for (int dr = 0; dr < 8; ++dr) {      // absolute row r = y0 - 3 + dr
        const int r = y0 - 3 + dr;
        if (r < 0 || r >= HH) continue;   // block-uniform branch (full exec below)
        const float* fr = fb + (size_t)r * WW;

        const float4 M = *reinterpret_cast<const float4*>(fr + x0);
        // window buf[1..10]: neighbors via DPP (zero-fill = image pad at xq 0/15)
        const float b1 = dpp_shr1(M.y), b2e = dpp_shr1(M.z), b3 = dpp_shr1(M.w);
        const float b8 = dpp_shl1(M.x), b9  = dpp_shl1(M.y), b10 = dpp_shl1(M.z);
        const float buf[12] = {0.f, b1, b2e, b3, M.x, M.y, M.z, M.w, b8, b9, b10, 0.f};

        #pragma unroll
        for (int ys = 0; ys < 2; ++ys) {
            const int i = dr - ys;        // compile-time tap row
            if (i < 0 || i >= 7) continue;
            if (i == 3) {                 // residual (row y0+ys always in-bounds)
                s[ys][0] += buf[4]; s[ys][1] += buf[5];
                s[ys][2] += buf[6]; s[ys][3] += buf[7];
            }
            #pragma unroll
            for (int jx = 0; jx < 7; ++jx) {
                const float4 w4 = *reinterpret_cast<const float4*>(&wg[ys][i * 7 + jx][x0]);
                s[ys][0] = fmaf(w4.x, buf[jx + 1], s[ys][0]);
                s[ys][1] = fmaf(w4.y, buf[jx + 2], s[ys][1]);
                s[ys][2] = fmaf(w4.z, buf[jx + 3], s[ys][2]);
                s[ys][3] = fmaf(w4.w, buf[jx + 4], s[ys][3]);
            }
        }
    }

    #pragma unroll
    for (int ys = 0; ys < 2; ++ys) {
        float4 o4; o4.x = s[ys][0]; o4.y = s[ys][1]; o4.z = s[ys][2]; o4.w = s[ys][3];
        *reinterpret_cast<float4*>(out + ((size_t)bb * CC + c) * HW
                                   + (size_t)(y0 + ys) * WW + x0) = o4;
    }
}

// ================= Fallback: fused single kernel (used only if ws too small) =================
__global__ __launch_bounds__(512, 1) void crossinv_fused_kernel(
    const float* __restrict__ feat, const float* __restrict__ guide,
    const float* __restrict__ w1, const float* __restrict__ gamma,
    const float* __restrict__ beta, const float* __restrict__ mean,
    const float* __restrict__ var, const float* __restrict__ w2,
    const float* __restrict__ b2, float* __restrict__ out)
{
    __shared__ float stf[RED][WW];
    __shared__ float wgf[K2][WW];
    const int bid  = blockIdx.x;
    const int bb   = bid >> 7;
    const int y    = (bid >> 1) & 63;
    const int gsel = bid & 1;
    const int lane = threadIdx.x & 63;
    const int wv   = __builtin_amdgcn_readfirstlane(threadIdx.x >> 6);

    const float* gptr = guide + (size_t)bb * CC * HW + (size_t)y * WW + lane;
    float acc[8];
    #pragma unroll
    for (int j = 0; j < 8; ++j) acc[j] = 0.f;
    for (int c0 = 0; c0 < CC; c0 += 4) {
        const float gv0 = gptr[(c0 + 0) * HW];
        const float gv1 = gptr[(c0 + 1) * HW];
        const float gv2 = gptr[(c0 + 2) * HW];
        const float gv3 = gptr[(c0 + 3) * HW];
        #pragma unroll
        for (int j = 0; j < 8; ++j) {
            const int o = wv + 8 * j;
            const float4 wr = *reinterpret_cast<const float4*>(w1 + o * CC + c0);
            acc[j] = fmaf(wr.x, gv0, acc[j]);
            acc[j] = fmaf(wr.y, gv1, acc[j]);
            acc[j] = fmaf(wr.z, gv2, acc[j]);
            acc[j] = fmaf(wr.w, gv3, acc[j]);
        }
    }
    #pragma unroll
    for (int j = 0; j < 8; ++j) {
        const int o = wv + 8 * j;
        const float sc = gamma[o] * rsqrtf(var[o] + 1e-5f);
        const float sh = beta[o] - mean[o] * sc;
        const float v  = fmaf(acc[j], sc, sh);
        stf[o][lane] = v > 0.f ? v : 0.f;
    }
    __syncthreads();
    for (int gi = 0; gi < 8; ++gi) {
        const int gg    = gsel * 8 + gi;
        const int obase = gg * K2;
        float accw[7];
        #pragma unroll
        for (int j = 0; j < 7; ++j) {
            const int o2 = wv + 8 * j;
            accw[j] = (o2 < K2) ? b2[obase + o2] : 0.f;
        }
        for (int r0 = 0; r0 < RED; r0 += 4) {
            const float t0 = stf[r0 + 0][lane];
            const float t1 = stf[r0 + 1][lane];
            const float t2 = stf[r0 + 2][lane];
            const float t3 = stf[r0 + 3][lane];
            #pragma unroll
            for (int j = 0; j < 7; ++j) {
                const int o2 = wv + 8 * j;
                if (o2 < K2) {
                    const float4 wr = *reinterpret_cast<const float4*>(
                        w2 + (size_t)(obase + o2) * RED + r0);
                    accw[j] = fmaf(wr.x, t0, accw[j]);
                    accw[j] = fmaf(wr.y, t1, accw[j]);
                    accw[j] = fmaf(wr.z, t2, accw[j]);
                    accw[j] = fmaf(wr.w, t3, accw[j]);
                }
            }
        }
        #pragma unroll
        for (int j = 0; j < 7; ++j) {
            const int o2 = wv + 8 * j;
            if (o2 < K2) wgf[o2][lane] = accw[j];
        }
        __syncthreads();
        #pragma unroll
        for (int cc2 = 0; cc2 < 2; ++cc2) {
            const int cc = wv * 2 + cc2;
            const int cch = gg * GCH + cc;
            const float* fbp = feat + ((size_t)bb * CC + cch) * HW;
            float sum = fbp[y * WW + lane];
            #pragma unroll
            for (int i = 0; i < 7; ++i) {
                const int yy = y + i - 3;
                if (yy < 0 || yy >= HH) continue;
                const float* frow = fbp + yy * WW;
                #pragma unroll
                for (int jx = 0; jx < 7; ++jx) {
                    const int xx = lane + jx - 3;
                    const float fv = (xx >= 0 && xx < WW) ? frow[xx] : 0.f;
                    sum = fmaf(wgf[i * 7 + jx][lane], fv, sum);
                }
            }
            out[((size_t)bb * CC + cch) * HW + (size_t)y * WW + lane] = sum;
        }
        __syncthreads();
    }
}

extern "C" void kernel_launch(void* const* d_in, const int* in_sizes, int n_in,
                              void* d_out, int out_size, void* d_ws, size_t ws_size,
                              hipStream_t stream) {
    const float* feat  = (const float*)d_in[0];
    const float* guide = (const float*)d_in[1];
    const float* w1    = (const float*)d_in[2];
    const float* gamma = (const float*)d_in[3];
    const float* beta  = (const float*)d_in[4];
    const float* mean  = (const float*)d_in[5];
    const float* var   = (const float*)d_in[6];
    const float* w2    = (const float*)d_in[7];
    const float* b2    = (const float*)d_in[8];
    float* out = (float*)d_out;

    const size_t need = (size_t)TT_ELTS * 2 + (size_t)W2BF_ROWS * RED * 2;  // ~1.1 MB
    if (ws_size >= need) {
        unsigned short* tt   = (unsigned short*)d_ws;
        unsigned short* w2bf = tt + TT_ELTS;
        hipLaunchKernelGGL(k1_kernel, dim3(308), dim3(128), 0, stream,
                           guide, w1, gamma, beta, mean, var, w2, tt, w2bf);
        hipLaunchKernelGGL(k2_inv_kernel, dim3(1024), dim3(256), 0, stream,
                           feat, tt, w2bf, b2, out);
    } else {
        hipLaunchKernelGGL(crossinv_fused_kernel, dim3(256), dim3(512), 0, stream,
                           feat, guide, w1, gamma, beta, mean, var, w2, b2, out);
    }
}